// Round 6
// baseline (727.463 us; speedup 1.0000x reference)
//
#include <hip/hip_runtime.h>
#include <hip/hip_fp16.h>
#include <hip/hip_cooperative_groups.h>

namespace cgns = cooperative_groups;

#define B_ 8
#define C_ 16
#define H_ 240
#define W_ 320
#define N_ (H_*W_)
#define TPB 300            // pixel tiles (256 px) per batch
#define NTILES (B_*TPB)    // 2400

__device__ __forceinline__ void twist2mat_dev(float w0, float w1, float w2, float R[9]) {
    float th = sqrtf(w0*w0 + w1*w1 + w2*w2) + 1e-12f;
    float ax = w0/th, ay = w1/th, az = w2/th;
    float s = sinf(th), c = cosf(th), ic = 1.0f - c;
    R[0] = 1.0f + ic*(ax*ax - 1.0f);
    R[1] = -s*az + ic*ax*ay;
    R[2] =  s*ay + ic*ax*az;
    R[3] =  s*az + ic*ax*ay;
    R[4] = 1.0f + ic*(ay*ay - 1.0f);
    R[5] = -s*ax + ic*ay*az;
    R[6] = -s*ay + ic*ax*az;
    R[7] =  s*ax + ic*ay*az;
    R[8] = 1.0f + ic*(az*az - 1.0f);
}

__device__ __forceinline__ unsigned pack_h2(float a, float b) {
    __half2 h = __floats2half2_rn(a, b);
    return *reinterpret_cast<unsigned*>(&h);
}
__device__ __forceinline__ float2 unpack_h2(unsigned u) {
    __half2 h = *reinterpret_cast<__half2*>(&u);
    return __half22float2(h);
}

// One damped-GN step from [21 upper-tri JtWJ | 6 rhs]; updates R,t.
__device__ __forceinline__ void solve_update(const float* ac, float R[9], float t[3]) {
    float M[6][7];
    {
        int idx = 0;
        #pragma unroll
        for (int k = 0; k < 6; k++)
            #pragma unroll
            for (int l = k; l < 6; l++) { M[k][l] = ac[idx]; M[l][k] = ac[idx]; idx++; }
    }
    const float trace = M[0][0]+M[1][1]+M[2][2]+M[3][3]+M[4][4]+M[5][5];
    const float lam = trace * 1e-6f;
    #pragma unroll
    for (int i = 0; i < 6; i++) { M[i][i] += lam; M[i][6] = ac[21+i]; }

    #pragma unroll
    for (int k = 0; k < 6; k++) {
        const float inv = 1.0f / M[k][k];
        #pragma unroll
        for (int i = k+1; i < 6; i++) {
            const float f = M[i][k] * inv;
            #pragma unroll
            for (int j = k; j < 7; j++) M[i][j] -= f * M[k][j];
        }
    }
    float xi[6];
    #pragma unroll
    for (int i = 5; i >= 0; i--) {
        float s = M[i][6];
        #pragma unroll
        for (int j = i+1; j < 6; j++) s -= M[i][j]*xi[j];
        xi[i] = s / M[i][i];
    }

    float dR[9];
    twist2mat_dev(-xi[0], -xi[1], -xi[2], dR);
    const float dt0 = -(dR[0]*xi[3] + dR[1]*xi[4] + dR[2]*xi[5]);
    const float dt1 = -(dR[3]*xi[3] + dR[4]*xi[4] + dR[5]*xi[5]);
    const float dt2 = -(dR[6]*xi[3] + dR[7]*xi[4] + dR[8]*xi[5]);

    const float nt0 = R[0]*dt0 + R[1]*dt1 + R[2]*dt2 + t[0];
    const float nt1 = R[3]*dt0 + R[4]*dt1 + R[5]*dt2 + t[1];
    const float nt2 = R[6]*dt0 + R[7]*dt1 + R[8]*dt2 + t[2];
    float nR[9];
    #pragma unroll
    for (int i = 0; i < 3; i++)
        #pragma unroll
        for (int j = 0; j < 3; j++)
            nR[i*3+j] = R[i*3+0]*dR[0*3+j] + R[i*3+1]*dR[1*3+j] + R[i*3+2]*dR[2*3+j];
    #pragma unroll
    for (int i = 0; i < 9; i++) R[i] = nR[i];
    t[0] = nt0; t[1] = nt1; t[2] = nt2;
}

__device__ __forceinline__ void build_RT(const float* twist0, const float* accum,
                                         int b, int iters, float R[9], float t[3]) {
    const float* w = twist0 + b*6;
    twist2mat_dev(w[0], w[1], w[2], R);
    t[0] = w[3]; t[1] = w[4]; t[2] = w[5];
    for (int j = 0; j < iters; j++)
        solve_update(accum + (size_t)(j*B_ + b)*27, R, t);
}

// Iteration-invariant precompute, 4 channels/thread:
//  P0h  : [b][cp=0..7][pix] uint4 = {h2(gx,gy), h2(x0,s0^2)} x 2 channels
//  X1S1h: [b][cg=0..3][pix] uint4 = h2(x1,s1) x 4 channels (gather target)
__launch_bounds__(256)
__global__ void precompute_kernel(const float* __restrict__ x0, const float* __restrict__ x1,
                                  const float* __restrict__ sigma0, const float* __restrict__ sigma1,
                                  uint4* __restrict__ P0h, uint4* __restrict__ X1S1h,
                                  float* __restrict__ accum)
{
    if (blockIdx.x == 0 && blockIdx.y == 0 && blockIdx.z == 0) {
        for (int k = threadIdx.x; k < 3*B_*27; k += 256) accum[k] = 0.0f;
    }
    const int pix = blockIdx.x*256 + threadIdx.x;
    const int cg = blockIdx.y;
    const int b = blockIdx.z;
    const int h = pix / W_, w = pix - h*W_;
    const int hm = max(h-1,0), hp = min(h+1,H_-1);
    const int wm = max(w-1,0), wp = min(w+1,W_-1);

    unsigned p0[8];
    unsigned xsp[4];
    #pragma unroll
    for (int i = 0; i < 4; i++) {
        const int c = cg*4 + i;
        const size_t base = ((size_t)(b*C_+c))*N_;
        const float* xc = x0 + base;
        const float tl = xc[hm*W_+wm], tc_ = xc[hm*W_+w], tr = xc[hm*W_+wp];
        const float ml = xc[h*W_+wm],                     mr = xc[h*W_+wp];
        const float bl = xc[hp*W_+wm], bc_ = xc[hp*W_+w], br = xc[hp*W_+wp];
        const float dx = tr - tl + 2.0f*(mr - ml) + (br - bl);
        const float dy = bl - tl + 2.0f*(bc_ - tc_) + (br - tr);
        const float mag = sqrtf(dx*dx + dy*dy + 1e-8f);
        const float s0v = sigma0[base + pix];
        p0[i*2+0] = pack_h2(dx/mag, dy/mag);
        p0[i*2+1] = pack_h2(xc[pix], s0v*s0v);
        xsp[i] = pack_h2(x1[base + pix], sigma1[base + pix]);
    }
    uint4 a; a.x = p0[0]; a.y = p0[1]; a.z = p0[2]; a.w = p0[3];
    uint4 bb; bb.x = p0[4]; bb.y = p0[5]; bb.z = p0[6]; bb.w = p0[7];
    P0h[((size_t)(b*8 + cg*2  ))*N_ + pix] = a;
    P0h[((size_t)(b*8 + cg*2+1))*N_ + pix] = bb;
    uint4 q; q.x = xsp[0]; q.y = xsp[1]; q.z = xsp[2]; q.w = xsp[3];
    X1S1h[((size_t)(b*4 + cg))*N_ + pix] = q;
}

// Per-pixel warp + occ-check + 16-channel weighted sums into acc[27].
__device__ __forceinline__ void accum_pixel(const uint4* __restrict__ P0b,
                                            const uint4* __restrict__ X1S1b,
                                            const float* __restrict__ invD0b,
                                            const float* __restrict__ invD1b,
                                            float fx, float fy, float cx, float cy,
                                            const float Rm[9], const float tv[3],
                                            int pix, float acc[27])
{
    const int h = pix / W_;
    const int w = pix - h*W_;
    const float px = ((float)w - cx) / fx;
    const float py = ((float)h - cy) / fy;
    const float d  = invD0b[pix];

    const float x_ = Rm[0]*px + Rm[1]*py + Rm[2] + tv[0]*d;
    const float y_ = Rm[3]*px + Rm[4]*py + Rm[5] + tv[1]*d;
    const float s_ = Rm[6]*px + Rm[7]*py + Rm[8] + tv[2]*d;
    const float u = x_/s_*fx + cx;
    const float v = y_/s_*fy + cy;
    const float inv_z = d / s_;

    const float uc = fminf(fmaxf(u, 0.0f), (float)(W_-1));
    const float vc = fminf(fmaxf(v, 0.0f), (float)(H_-1));
    const float x0f = floorf(uc), y0f = floorf(vc);
    const float wx = uc - x0f, wy = vc - y0f;
    const int x0i = (int)x0f, y0i = (int)y0f;
    const int x1i = min(x0i+1, W_-1), y1i = min(y0i+1, H_-1);
    const float w00 = (1.0f-wx)*(1.0f-wy), w01 = wx*(1.0f-wy);
    const float w10 = (1.0f-wx)*wy,        w11 = wx*wy;
    const int i00 = y0i*W_+x0i, i01 = y0i*W_+x1i, i10 = y1i*W_+x0i, i11 = y1i*W_+x1i;

    const float zw = invD1b[i00]*w00 + invD1b[i01]*w01 + invD1b[i10]*w10 + invD1b[i11]*w11;
    const bool inlier = inv_z > zw - 0.1f;
    const bool inview = (u > 0.0f) && (u < (float)W_) && (v > 0.0f) && (v < (float)H_);
    if (!(inlier && inview)) return;

    const float xy = px*py;
    const float Av[6] = { -xy*fx, (1.0f+px*px)*fx, -py*fx, d*fx, 0.0f, -d*px*fx };
    const float Bv[6] = { -(1.0f+py*py)*fy, xy*fy, px*fy, 0.0f, d*fy, -d*py*fy };

    float Swxx=0.f, Swxy=0.f, Swyy=0.f, Srx=0.f, Sry=0.f;

#define CH(gword, xword, t00, t01, t10, t11) { \
    const float2 g  = unpack_h2(gword); \
    const float2 xs = unpack_h2(xword); \
    const float2 a00 = unpack_h2(t00), a01 = unpack_h2(t01), \
                 a10 = unpack_h2(t10), a11 = unpack_h2(t11); \
    const float fr = a00.x*w00 + a01.x*w01 + a10.x*w10 + a11.x*w11; \
    const float sr = a00.y*w00 + a01.y*w01 + a10.y*w10 + a11.y*w11; \
    const float inv_s2 = 1.0f/(sr*sr + xs.y); \
    const float res = fr - xs.x; \
    const float gxw = g.x*inv_s2, gyw = g.y*inv_s2; \
    Swxx += g.x*gxw; Swxy += g.x*gyw; Swyy += g.y*gyw; \
    Srx  += res*gxw; Sry  += res*gyw; }

    // unroll 2 (not 4): halves in-flight gather registers -> better occupancy
    #pragma unroll 2
    for (int cg = 0; cg < 4; cg++) {
        const uint4 pA = P0b[(size_t)(cg*2  )*N_ + pix];
        const uint4 pB = P0b[(size_t)(cg*2+1)*N_ + pix];
        const uint4* xsb = X1S1b + (size_t)cg*N_;
        const uint4 q00 = xsb[i00], q01 = xsb[i01], q10 = xsb[i10], q11 = xsb[i11];
        CH(pA.x, pA.y, q00.x, q01.x, q10.x, q11.x)
        CH(pA.z, pA.w, q00.y, q01.y, q10.y, q11.y)
        CH(pB.x, pB.y, q00.z, q01.z, q10.z, q11.z)
        CH(pB.z, pB.w, q00.w, q01.w, q10.w, q11.w)
    }
#undef CH

    int idx = 0;
    #pragma unroll
    for (int k = 0; k < 6; k++) {
        #pragma unroll
        for (int l = k; l < 6; l++) {
            acc[idx++] += Swxx*Av[k]*Av[l] + Swxy*(Av[k]*Bv[l] + Bv[k]*Av[l]) + Swyy*Bv[k]*Bv[l];
        }
    }
    #pragma unroll
    for (int k = 0; k < 6; k++) acc[21+k] += Srx*Av[k] + Sry*Bv[k];
}

__device__ __forceinline__ void block_reduce_atomic(float acc[27], float* dst,
                                                    float red[4][27], int tid)
{
    const int lane = tid & 63;
    const int wave = tid >> 6;
    #pragma unroll
    for (int j = 0; j < 27; j++) {
        float vv = acc[j];
        vv += __shfl_down(vv, 32);
        vv += __shfl_down(vv, 16);
        vv += __shfl_down(vv, 8);
        vv += __shfl_down(vv, 4);
        vv += __shfl_down(vv, 2);
        vv += __shfl_down(vv, 1);
        if (lane == 0) red[wave][j] = vv;
    }
    __syncthreads();
    if (tid < 27) {
        float s = red[0][tid] + red[1][tid] + red[2][tid] + red[3][tid];
        atomicAdd(&dst[tid], s);
    }
    __syncthreads();   // red[] reused next tile
}

// All 3 LM iterations + finalize in one cooperative launch.
// Grid-stride over 2400 (b,tile) pairs -> correct for ANY grid size.
__launch_bounds__(256)
__global__ void solve_iters_coop(const uint4* __restrict__ P0h, const uint4* __restrict__ X1S1h,
                                 const float* __restrict__ invD0, const float* __restrict__ invD1,
                                 const float* __restrict__ Kmat, const float* __restrict__ twist0,
                                 float* __restrict__ accum, float* __restrict__ out)
{
    cgns::grid_group grid = cgns::this_grid();
    const int tid = threadIdx.x;
    __shared__ float red[4][27];

    for (int it = 0; it < 3; ++it) {
        for (int tile = blockIdx.x; tile < NTILES; tile += gridDim.x) {
            const int b  = tile / TPB;
            const int pt = tile - b*TPB;
            const int pix = pt*256 + tid;

            float Rm[9], tv[3];
            build_RT(twist0, accum, b, it, Rm, tv);

            const float fx = Kmat[b*4+0], fy = Kmat[b*4+1], cx = Kmat[b*4+2], cy = Kmat[b*4+3];
            float acc[27];
            #pragma unroll
            for (int j = 0; j < 27; j++) acc[j] = 0.0f;

            accum_pixel(P0h + (size_t)b*8*N_, X1S1h + (size_t)b*4*N_,
                        invD0 + (size_t)b*N_, invD1 + (size_t)b*N_,
                        fx, fy, cx, cy, Rm, tv, pix, acc);

            block_reduce_atomic(acc, &accum[(size_t)(it*B_ + b)*27], red, tid);
        }
        __threadfence();
        grid.sync();
    }

    if (blockIdx.x == 0 && tid < B_) {
        float Rm[9], tv[3];
        build_RT(twist0, accum, tid, 3, Rm, tv);
        float* ob = out + tid*12;
        #pragma unroll
        for (int i = 0; i < 9; i++) ob[i] = Rm[i];
        ob[9] = tv[0]; ob[10] = tv[1]; ob[11] = tv[2];
    }
}

// ---- Fallback path (round-4 structure): per-iteration dispatch ----
__launch_bounds__(256)
__global__ void iter_kernel_fb(const uint4* __restrict__ P0h, const uint4* __restrict__ X1S1h,
                               const float* __restrict__ invD0, const float* __restrict__ invD1,
                               const float* __restrict__ Kmat, const float* __restrict__ twist0,
                               float* __restrict__ accum, int it)
{
    const int b = blockIdx.y;
    const int pix = blockIdx.x*256 + threadIdx.x;
    const int tid = threadIdx.x;
    __shared__ float red[4][27];

    float Rm[9], tv[3];
    build_RT(twist0, accum, b, it, Rm, tv);

    const float fx = Kmat[b*4+0], fy = Kmat[b*4+1], cx = Kmat[b*4+2], cy = Kmat[b*4+3];
    float acc[27];
    #pragma unroll
    for (int j = 0; j < 27; j++) acc[j] = 0.0f;

    accum_pixel(P0h + (size_t)b*8*N_, X1S1h + (size_t)b*4*N_,
                invD0 + (size_t)b*N_, invD1 + (size_t)b*N_,
                fx, fy, cx, cy, Rm, tv, pix, acc);

    block_reduce_atomic(acc, &accum[(size_t)(it*B_ + b)*27], red, tid);
}

__global__ void finalize_kernel(const float* __restrict__ twist0, const float* __restrict__ accum,
                                float* __restrict__ out)
{
    const int b = threadIdx.x;
    if (b >= B_) return;
    float Rm[9], tv[3];
    build_RT(twist0, accum, b, 3, Rm, tv);
    float* ob = out + b*12;
    #pragma unroll
    for (int i = 0; i < 9; i++) ob[i] = Rm[i];
    ob[9] = tv[0]; ob[10] = tv[1]; ob[11] = tv[2];
}

extern "C" void kernel_launch(void* const* d_in, const int* in_sizes, int n_in,
                              void* d_out, int out_size, void* d_ws, size_t ws_size,
                              hipStream_t stream) {
    const float* twist0 = (const float*)d_in[0];
    const float* x0     = (const float*)d_in[1];
    const float* x1     = (const float*)d_in[2];
    const float* invD0  = (const float*)d_in[3];
    const float* invD1  = (const float*)d_in[4];
    const float* sigma0 = (const float*)d_in[5];
    const float* sigma1 = (const float*)d_in[6];
    const float* Kmat   = (const float*)d_in[7];
    float* out = (float*)d_out;

    const size_t p0_bytes = (size_t)B_*8*N_*sizeof(uint4);   // 78.6 MB
    const size_t xs_bytes = (size_t)B_*4*N_*sizeof(uint4);   // 39.3 MB

    uint4* P0h   = (uint4*)d_ws;
    uint4* X1S1h = (uint4*)((char*)d_ws + p0_bytes);
    float* accum = (float*)((char*)d_ws + p0_bytes + xs_bytes);  // 3*B_*27 floats

    hipLaunchKernelGGL(precompute_kernel, dim3(N_/256, 4, B_), dim3(256), 0, stream,
                       x0, x1, sigma0, sigma1, P0h, X1S1h, accum);

    // Occupancy-derived cooperative grid size (host-side queries: graph-safe).
    int blocksPerCU = 0;
    (void)hipOccupancyMaxActiveBlocksPerMultiprocessor(&blocksPerCU, solve_iters_coop, 256, 0);
    int numCU = 0;
    (void)hipDeviceGetAttribute(&numCU, hipDeviceAttributeMultiprocessorCount, 0);

    bool coop_ok = false;
    if (blocksPerCU > 0 && numCU > 0) {
        int nblk = blocksPerCU * numCU;
        if (nblk > NTILES) nblk = NTILES;
        void* args[] = { (void*)&P0h, (void*)&X1S1h, (void*)&invD0, (void*)&invD1,
                         (void*)&Kmat, (void*)&twist0, (void*)&accum, (void*)&out };
        hipError_t e = hipLaunchCooperativeKernel((const void*)solve_iters_coop,
                                                  dim3(nblk), dim3(256), args, 0, stream);
        coop_ok = (e == hipSuccess);
    }

    if (!coop_ok) {
        dim3 grid(TPB, B_);
        for (int it = 0; it < 3; ++it) {
            hipLaunchKernelGGL(iter_kernel_fb, grid, dim3(256), 0, stream,
                               P0h, X1S1h, invD0, invD1, Kmat, twist0, accum, it);
        }
        hipLaunchKernelGGL(finalize_kernel, dim3(1), dim3(64), 0, stream, twist0, accum, out);
    }
}

// Round 7
// 720.769 us; speedup vs baseline: 1.0093x; 1.0093x over previous
//
#include <hip/hip_runtime.h>
#include <hip/hip_fp16.h>

#define B_ 8
#define C_ 16
#define H_ 240
#define W_ 320
#define N_ (H_*W_)
#define K1_BLOCKS_PER_B (300*4)   // grid (300,4,8) -> 1200 blocks per batch
#define K2_BLOCKS_PER_B 300       // grid (300,8)

__device__ __forceinline__ void twist2mat_dev(float w0, float w1, float w2, float R[9]) {
    float th = sqrtf(w0*w0 + w1*w1 + w2*w2) + 1e-12f;
    float ax = w0/th, ay = w1/th, az = w2/th;
    float s = sinf(th), c = cosf(th), ic = 1.0f - c;
    R[0] = 1.0f + ic*(ax*ax - 1.0f);
    R[1] = -s*az + ic*ax*ay;
    R[2] =  s*ay + ic*ax*az;
    R[3] =  s*az + ic*ax*ay;
    R[4] = 1.0f + ic*(ay*ay - 1.0f);
    R[5] = -s*ax + ic*ay*az;
    R[6] = -s*ay + ic*ax*az;
    R[7] =  s*ax + ic*ay*az;
    R[8] = 1.0f + ic*(az*az - 1.0f);
}

__device__ __forceinline__ unsigned pack_h2(float a, float b) {
    __half2 h = __floats2half2_rn(a, b);
    return *reinterpret_cast<unsigned*>(&h);
}
__device__ __forceinline__ float2 unpack_h2(unsigned u) {
    __half2 h = *reinterpret_cast<__half2*>(&u);
    return __half22float2(h);
}

// One damped-GN step from [21 upper-tri JtWJ | 6 rhs]; updates R,t in place.
__device__ __forceinline__ void solve_update(const float* sums, float R[9], float t[3]) {
    float M[6][7];
    {
        int idx = 0;
        #pragma unroll
        for (int k = 0; k < 6; k++)
            #pragma unroll
            for (int l = k; l < 6; l++) { M[k][l] = sums[idx]; M[l][k] = sums[idx]; idx++; }
    }
    const float trace = M[0][0]+M[1][1]+M[2][2]+M[3][3]+M[4][4]+M[5][5];
    const float lam = trace * 1e-6f;
    #pragma unroll
    for (int i = 0; i < 6; i++) { M[i][i] += lam; M[i][6] = sums[21+i]; }

    #pragma unroll
    for (int k = 0; k < 6; k++) {
        const float inv = 1.0f / M[k][k];
        #pragma unroll
        for (int i = k+1; i < 6; i++) {
            const float f = M[i][k] * inv;
            #pragma unroll
            for (int j = k; j < 7; j++) M[i][j] -= f * M[k][j];
        }
    }
    float xi[6];
    #pragma unroll
    for (int i = 5; i >= 0; i--) {
        float s = M[i][6];
        #pragma unroll
        for (int j = i+1; j < 6; j++) s -= M[i][j]*xi[j];
        xi[i] = s / M[i][i];
    }

    float dR[9];
    twist2mat_dev(-xi[0], -xi[1], -xi[2], dR);
    const float dt0 = -(dR[0]*xi[3] + dR[1]*xi[4] + dR[2]*xi[5]);
    const float dt1 = -(dR[3]*xi[3] + dR[4]*xi[4] + dR[5]*xi[5]);
    const float dt2 = -(dR[6]*xi[3] + dR[7]*xi[4] + dR[8]*xi[5]);

    const float nt0 = R[0]*dt0 + R[1]*dt1 + R[2]*dt2 + t[0];
    const float nt1 = R[3]*dt0 + R[4]*dt1 + R[5]*dt2 + t[1];
    const float nt2 = R[6]*dt0 + R[7]*dt1 + R[8]*dt2 + t[2];
    float nR[9];
    #pragma unroll
    for (int i = 0; i < 3; i++)
        #pragma unroll
        for (int j = 0; j < 3; j++)
            nR[i*3+j] = R[i*3+0]*dR[0*3+j] + R[i*3+1]*dR[1*3+j] + R[i*3+2]*dR[2*3+j];
    #pragma unroll
    for (int i = 0; i < 9; i++) R[i] = nR[i];
    t[0] = nt0; t[1] = nt1; t[2] = nt2;
}

__device__ __forceinline__ void block_reduce_atomic(float acc[27], float* dst,
                                                    float red[4][27], int tid)
{
    const int lane = tid & 63;
    const int wave = tid >> 6;
    #pragma unroll
    for (int j = 0; j < 27; j++) {
        float vv = acc[j];
        vv += __shfl_down(vv, 32);
        vv += __shfl_down(vv, 16);
        vv += __shfl_down(vv, 8);
        vv += __shfl_down(vv, 4);
        vv += __shfl_down(vv, 2);
        vv += __shfl_down(vv, 1);
        if (lane == 0) red[wave][j] = vv;
    }
    __syncthreads();
    if (tid < 27) {
        float s = red[0][tid] + red[1][tid] + red[2][tid] + red[3][tid];
        atomicAdd(&dst[tid], s);
    }
}

// Last-block epilogue: read device-coherent sums, do the 6x6 solve, write RT_{it+1}
// (or the final output for it==2). Executed redundantly by wave 0 of the last block.
__device__ __forceinline__ void epilogue_solve(int it, int b,
                                               const float* __restrict__ twist0,
                                               float* __restrict__ accum,
                                               float* __restrict__ RTbuf,
                                               float* __restrict__ out, int lane)
{
    __threadfence();
    float* ac = accum + (size_t)(it*B_ + b)*27;
    float sv = 0.0f;
    if (lane < 27) sv = atomicAdd(&ac[lane], 0.0f);   // device-coherent read
    float sums[27];
    #pragma unroll
    for (int j = 0; j < 27; j++) sums[j] = __shfl(sv, j);

    float R[9], t[3];
    if (it == 0) {
        const float* w = twist0 + b*6;
        twist2mat_dev(w[0], w[1], w[2], R);
        t[0] = w[3]; t[1] = w[4]; t[2] = w[5];
    } else {
        const float* rt = RTbuf + (size_t)(it*B_ + b)*12;
        #pragma unroll
        for (int i = 0; i < 9; i++) R[i] = rt[i];
        t[0] = rt[9]; t[1] = rt[10]; t[2] = rt[11];
    }
    solve_update(sums, R, t);

    if (lane == 0) {
        float* dst = (it == 2) ? (out + b*12) : (RTbuf + (size_t)((it+1)*B_ + b)*12);
        #pragma unroll
        for (int i = 0; i < 9; i++) dst[i] = R[i];
        dst[9] = t[0]; dst[10] = t[1]; dst[11] = t[2];
    }
}

// K1: precompute packed tensors AND accumulate iteration 0 (R,t from twist0 only;
// gathers read the raw fp32 x1/sigma1 -> no dependency on packed output).
// grid (300, 4, 8), 4 channels per thread.
__launch_bounds__(256)
__global__ void fused_pre_iter0(const float* __restrict__ x0, const float* __restrict__ x1,
                                const float* __restrict__ sigma0, const float* __restrict__ sigma1,
                                const float* __restrict__ invD0, const float* __restrict__ invD1,
                                const float* __restrict__ Kmat, const float* __restrict__ twist0,
                                uint4* __restrict__ P0h, uint4* __restrict__ X1S1h,
                                float* __restrict__ accum, float* __restrict__ RTbuf,
                                unsigned* __restrict__ tickets, float* __restrict__ out)
{
    const int pix = blockIdx.x*256 + threadIdx.x;
    const int cg = blockIdx.y;
    const int b = blockIdx.z;
    const int tid = threadIdx.x;
    const int h = pix / W_, w = pix - h*W_;
    const int hm = max(h-1,0), hp = min(h+1,H_-1);
    const int wm = max(w-1,0), wp = min(w+1,W_-1);

    float gx[4], gy[4], x0c[4], s0sq[4];
    unsigned p0[8], xsp[4];
    #pragma unroll
    for (int i = 0; i < 4; i++) {
        const int c = cg*4 + i;
        const size_t base = ((size_t)(b*C_+c))*N_;
        const float* xc = x0 + base;
        const float tl = xc[hm*W_+wm], tc_ = xc[hm*W_+w], tr = xc[hm*W_+wp];
        const float ml = xc[h*W_+wm],                     mr = xc[h*W_+wp];
        const float bl = xc[hp*W_+wm], bc_ = xc[hp*W_+w], br = xc[hp*W_+wp];
        const float dx = tr - tl + 2.0f*(mr - ml) + (br - bl);
        const float dy = bl - tl + 2.0f*(bc_ - tc_) + (br - tr);
        const float mag = sqrtf(dx*dx + dy*dy + 1e-8f);
        gx[i] = dx/mag; gy[i] = dy/mag;
        x0c[i] = xc[pix];
        const float s0v = sigma0[base + pix];
        s0sq[i] = s0v*s0v;
        p0[i*2+0] = pack_h2(gx[i], gy[i]);
        p0[i*2+1] = pack_h2(x0c[i], s0sq[i]);
        xsp[i] = pack_h2(x1[base + pix], sigma1[base + pix]);
    }
    {
        uint4 a; a.x = p0[0]; a.y = p0[1]; a.z = p0[2]; a.w = p0[3];
        uint4 bb; bb.x = p0[4]; bb.y = p0[5]; bb.z = p0[6]; bb.w = p0[7];
        P0h[((size_t)(b*8 + cg*2  ))*N_ + pix] = a;
        P0h[((size_t)(b*8 + cg*2+1))*N_ + pix] = bb;
        uint4 q; q.x = xsp[0]; q.y = xsp[1]; q.z = xsp[2]; q.w = xsp[3];
        X1S1h[((size_t)(b*4 + cg))*N_ + pix] = q;
    }

    // ---- iteration 0 accumulation (this thread's 4 channels) ----
    float Rm[9], tv[3];
    {
        const float* wv = twist0 + b*6;
        twist2mat_dev(wv[0], wv[1], wv[2], Rm);
        tv[0] = wv[3]; tv[1] = wv[4]; tv[2] = wv[5];
    }
    const float fx = Kmat[b*4+0], fy = Kmat[b*4+1], cx = Kmat[b*4+2], cy = Kmat[b*4+3];
    const float px = ((float)w - cx) / fx;
    const float py = ((float)h - cy) / fy;
    const float d  = invD0[(size_t)b*N_ + pix];

    const float x_ = Rm[0]*px + Rm[1]*py + Rm[2] + tv[0]*d;
    const float y_ = Rm[3]*px + Rm[4]*py + Rm[5] + tv[1]*d;
    const float s_ = Rm[6]*px + Rm[7]*py + Rm[8] + tv[2]*d;
    const float u = x_/s_*fx + cx;
    const float v = y_/s_*fy + cy;
    const float inv_z = d / s_;

    const float uc = fminf(fmaxf(u, 0.0f), (float)(W_-1));
    const float vc = fminf(fmaxf(v, 0.0f), (float)(H_-1));
    const float x0f = floorf(uc), y0f = floorf(vc);
    const float wx = uc - x0f, wy = vc - y0f;
    const int x0i = (int)x0f, y0i = (int)y0f;
    const int x1i = min(x0i+1, W_-1), y1i = min(y0i+1, H_-1);
    const float w00 = (1.0f-wx)*(1.0f-wy), w01 = wx*(1.0f-wy);
    const float w10 = (1.0f-wx)*wy,        w11 = wx*wy;
    const int i00 = y0i*W_+x0i, i01 = y0i*W_+x1i, i10 = y1i*W_+x0i, i11 = y1i*W_+x1i;

    const float* dz = invD1 + (size_t)b*N_;
    const float zw = dz[i00]*w00 + dz[i01]*w01 + dz[i10]*w10 + dz[i11]*w11;
    const bool inlier = inv_z > zw - 0.1f;
    const bool inview = (u > 0.0f) && (u < (float)W_) && (v > 0.0f) && (v < (float)H_);

    float acc[27];
    #pragma unroll
    for (int j = 0; j < 27; j++) acc[j] = 0.0f;

    if (inlier && inview) {
        const float xy = px*py;
        const float Av[6] = { -xy*fx, (1.0f+px*px)*fx, -py*fx, d*fx, 0.0f, -d*px*fx };
        const float Bv[6] = { -(1.0f+py*py)*fy, xy*fy, px*fy, 0.0f, d*fy, -d*py*fy };

        float Swxx=0.f, Swxy=0.f, Swyy=0.f, Srx=0.f, Sry=0.f;
        #pragma unroll
        for (int i = 0; i < 4; i++) {
            const int c = cg*4 + i;
            const size_t base = ((size_t)(b*C_+c))*N_;
            const float* x1c = x1 + base;
            const float* s1c = sigma1 + base;
            const float fr = x1c[i00]*w00 + x1c[i01]*w01 + x1c[i10]*w10 + x1c[i11]*w11;
            const float sr = s1c[i00]*w00 + s1c[i01]*w01 + s1c[i10]*w10 + s1c[i11]*w11;
            const float inv_s2 = 1.0f / (sr*sr + s0sq[i]);
            const float res = fr - x0c[i];
            const float gxw = gx[i]*inv_s2, gyw = gy[i]*inv_s2;
            Swxx += gx[i]*gxw;
            Swxy += gx[i]*gyw;
            Swyy += gy[i]*gyw;
            Srx  += res*gxw;
            Sry  += res*gyw;
        }
        int idx = 0;
        #pragma unroll
        for (int k = 0; k < 6; k++) {
            #pragma unroll
            for (int l = k; l < 6; l++) {
                acc[idx++] = Swxx*Av[k]*Av[l] + Swxy*(Av[k]*Bv[l] + Bv[k]*Av[l]) + Swyy*Bv[k]*Bv[l];
            }
        }
        #pragma unroll
        for (int k = 0; k < 6; k++) acc[21+k] = Srx*Av[k] + Sry*Bv[k];
    }

    __shared__ float red[4][27];
    block_reduce_atomic(acc, &accum[(size_t)(0*B_ + b)*27], red, tid);

    __shared__ unsigned lastFlag;
    if (tid == 0) {
        __threadfence();
        unsigned prev = atomicAdd(&tickets[0*B_ + b], 1u);
        lastFlag = (prev == K1_BLOCKS_PER_B - 1) ? 1u : 0u;
    }
    __syncthreads();
    if (lastFlag && tid < 64) {
        epilogue_solve(0, b, twist0, accum, RTbuf, out, tid);
    }
}

// K2/K3: lean iteration kernel (RT read as 12 uniform floats from ws) + last-block solve.
__launch_bounds__(256)
__global__ void iter_mid(const uint4* __restrict__ P0h, const uint4* __restrict__ X1S1h,
                         const float* __restrict__ invD0, const float* __restrict__ invD1,
                         const float* __restrict__ Kmat, const float* __restrict__ twist0,
                         float* __restrict__ accum, float* __restrict__ RTbuf,
                         unsigned* __restrict__ tickets, float* __restrict__ out, int it)
{
    const int b = blockIdx.y;
    const int pix = blockIdx.x*256 + threadIdx.x;
    const int tid = threadIdx.x;
    const int h = pix / W_;
    const int w = pix - h*W_;

    const float* rt = RTbuf + (size_t)(it*B_ + b)*12;
    const float R00=rt[0],R01=rt[1],R02=rt[2],R10=rt[3],R11=rt[4],R12=rt[5],
                R20=rt[6],R21=rt[7],R22=rt[8];
    const float t0=rt[9], t1=rt[10], t2=rt[11];
    const float fx = Kmat[b*4+0], fy = Kmat[b*4+1], cx = Kmat[b*4+2], cy = Kmat[b*4+3];

    const float px = ((float)w - cx) / fx;
    const float py = ((float)h - cy) / fy;
    const float d  = invD0[(size_t)b*N_ + pix];

    const float x_ = R00*px + R01*py + R02 + t0*d;
    const float y_ = R10*px + R11*py + R12 + t1*d;
    const float s_ = R20*px + R21*py + R22 + t2*d;
    const float u = x_/s_*fx + cx;
    const float v = y_/s_*fy + cy;
    const float inv_z = d / s_;

    const float uc = fminf(fmaxf(u, 0.0f), (float)(W_-1));
    const float vc = fminf(fmaxf(v, 0.0f), (float)(H_-1));
    const float x0f = floorf(uc), y0f = floorf(vc);
    const float wx = uc - x0f, wy = vc - y0f;
    const int x0i = (int)x0f, y0i = (int)y0f;
    const int x1i = min(x0i+1, W_-1), y1i = min(y0i+1, H_-1);
    const float w00 = (1.0f-wx)*(1.0f-wy), w01 = wx*(1.0f-wy);
    const float w10 = (1.0f-wx)*wy,        w11 = wx*wy;
    const int i00 = y0i*W_+x0i, i01 = y0i*W_+x1i, i10 = y1i*W_+x0i, i11 = y1i*W_+x1i;

    const float* dz = invD1 + (size_t)b*N_;
    const float zw = dz[i00]*w00 + dz[i01]*w01 + dz[i10]*w10 + dz[i11]*w11;
    const bool inlier = inv_z > zw - 0.1f;
    const bool inview = (u > 0.0f) && (u < (float)W_) && (v > 0.0f) && (v < (float)H_);

    float acc[27];
    #pragma unroll
    for (int j = 0; j < 27; j++) acc[j] = 0.0f;

    if (inlier && inview) {
        const float xy = px*py;
        const float Av[6] = { -xy*fx, (1.0f+px*px)*fx, -py*fx, d*fx, 0.0f, -d*px*fx };
        const float Bv[6] = { -(1.0f+py*py)*fy, xy*fy, px*fy, 0.0f, d*fy, -d*py*fy };

        float Swxx=0.f, Swxy=0.f, Swyy=0.f, Srx=0.f, Sry=0.f;
        const uint4* P0b   = P0h   + (size_t)b*8*N_;
        const uint4* X1S1b = X1S1h + (size_t)b*4*N_;

#define CH(gword, xword, t00, t01, t10, t11) { \
        const float2 g  = unpack_h2(gword); \
        const float2 xs = unpack_h2(xword); \
        const float2 a00 = unpack_h2(t00), a01 = unpack_h2(t01), \
                     a10 = unpack_h2(t10), a11 = unpack_h2(t11); \
        const float fr = a00.x*w00 + a01.x*w01 + a10.x*w10 + a11.x*w11; \
        const float sr = a00.y*w00 + a01.y*w01 + a10.y*w10 + a11.y*w11; \
        const float inv_s2 = 1.0f/(sr*sr + xs.y); \
        const float res = fr - xs.x; \
        const float gxw = g.x*inv_s2, gyw = g.y*inv_s2; \
        Swxx += g.x*gxw; Swxy += g.x*gyw; Swyy += g.y*gyw; \
        Srx  += res*gxw; Sry  += res*gyw; }

        #pragma unroll 2
        for (int cgi = 0; cgi < 4; cgi++) {
            const uint4 pA = P0b[(size_t)(cgi*2  )*N_ + pix];
            const uint4 pB = P0b[(size_t)(cgi*2+1)*N_ + pix];
            const uint4* xsb = X1S1b + (size_t)cgi*N_;
            const uint4 q00 = xsb[i00], q01 = xsb[i01], q10 = xsb[i10], q11 = xsb[i11];
            CH(pA.x, pA.y, q00.x, q01.x, q10.x, q11.x)
            CH(pA.z, pA.w, q00.y, q01.y, q10.y, q11.y)
            CH(pB.x, pB.y, q00.z, q01.z, q10.z, q11.z)
            CH(pB.z, pB.w, q00.w, q01.w, q10.w, q11.w)
        }
#undef CH

        int idx = 0;
        #pragma unroll
        for (int k = 0; k < 6; k++) {
            #pragma unroll
            for (int l = k; l < 6; l++) {
                acc[idx++] = Swxx*Av[k]*Av[l] + Swxy*(Av[k]*Bv[l] + Bv[k]*Av[l]) + Swyy*Bv[k]*Bv[l];
            }
        }
        #pragma unroll
        for (int k = 0; k < 6; k++) acc[21+k] = Srx*Av[k] + Sry*Bv[k];
    }

    __shared__ float red[4][27];
    block_reduce_atomic(acc, &accum[(size_t)(it*B_ + b)*27], red, tid);

    __shared__ unsigned lastFlag;
    if (tid == 0) {
        __threadfence();
        unsigned prev = atomicAdd(&tickets[it*B_ + b], 1u);
        lastFlag = (prev == K2_BLOCKS_PER_B - 1) ? 1u : 0u;
    }
    __syncthreads();
    if (lastFlag && tid < 64) {
        epilogue_solve(it, b, twist0, accum, RTbuf, out, tid);
    }
}

extern "C" void kernel_launch(void* const* d_in, const int* in_sizes, int n_in,
                              void* d_out, int out_size, void* d_ws, size_t ws_size,
                              hipStream_t stream) {
    const float* twist0 = (const float*)d_in[0];
    const float* x0     = (const float*)d_in[1];
    const float* x1     = (const float*)d_in[2];
    const float* invD0  = (const float*)d_in[3];
    const float* invD1  = (const float*)d_in[4];
    const float* sigma0 = (const float*)d_in[5];
    const float* sigma1 = (const float*)d_in[6];
    const float* Kmat   = (const float*)d_in[7];
    float* out = (float*)d_out;

    const size_t p0_bytes = (size_t)B_*8*N_*sizeof(uint4);   // 78.6 MB
    const size_t xs_bytes = (size_t)B_*4*N_*sizeof(uint4);   // 39.3 MB

    uint4* P0h   = (uint4*)d_ws;
    uint4* X1S1h = (uint4*)((char*)d_ws + p0_bytes);
    char*  smal  = (char*)d_ws + p0_bytes + xs_bytes;
    float*    accum   = (float*)smal;                         // 3*B_*27 floats
    float*    RTbuf   = accum + 3*B_*27;                      // 3*B_*12 floats
    unsigned* tickets = (unsigned*)(RTbuf + 3*B_*12);         // 3*B_ uints
    const size_t small_bytes = (3*B_*27 + 3*B_*12)*sizeof(float) + 3*B_*sizeof(unsigned);

    hipMemsetAsync(smal, 0, small_bytes, stream);

    hipLaunchKernelGGL(fused_pre_iter0, dim3(N_/256, 4, B_), dim3(256), 0, stream,
                       x0, x1, sigma0, sigma1, invD0, invD1, Kmat, twist0,
                       P0h, X1S1h, accum, RTbuf, tickets, out);

    dim3 grid(N_/256, B_);
    hipLaunchKernelGGL(iter_mid, grid, dim3(256), 0, stream,
                       P0h, X1S1h, invD0, invD1, Kmat, twist0,
                       accum, RTbuf, tickets, out, 1);
    hipLaunchKernelGGL(iter_mid, grid, dim3(256), 0, stream,
                       P0h, X1S1h, invD0, invD1, Kmat, twist0,
                       accum, RTbuf, tickets, out, 2);
}

// Round 8
// 469.210 us; speedup vs baseline: 1.5504x; 1.5361x over previous
//
#include <hip/hip_runtime.h>
#include <hip/hip_fp16.h>

#define B_ 8
#define C_ 16
#define H_ 240
#define W_ 320
#define N_ (H_*W_)
#define ITER_BLOCKS_PER_B (N_/256)   // 1200

__device__ __forceinline__ void twist2mat_dev(float w0, float w1, float w2, float R[9]) {
    float th = sqrtf(w0*w0 + w1*w1 + w2*w2) + 1e-12f;
    float ax = w0/th, ay = w1/th, az = w2/th;
    float s = sinf(th), c = cosf(th), ic = 1.0f - c;
    R[0] = 1.0f + ic*(ax*ax - 1.0f);
    R[1] = -s*az + ic*ax*ay;
    R[2] =  s*ay + ic*ax*az;
    R[3] =  s*az + ic*ax*ay;
    R[4] = 1.0f + ic*(ay*ay - 1.0f);
    R[5] = -s*ax + ic*ay*az;
    R[6] = -s*ay + ic*ax*az;
    R[7] =  s*ax + ic*ay*az;
    R[8] = 1.0f + ic*(az*az - 1.0f);
}

__device__ __forceinline__ unsigned pack_h2(float a, float b) {
    __half2 h = __floats2half2_rn(a, b);
    return *reinterpret_cast<unsigned*>(&h);
}
__device__ __forceinline__ float2 unpack_h2(unsigned u) {
    __half2 h = *reinterpret_cast<__half2*>(&u);
    return __half22float2(h);
}

// One damped-GN step from [21 upper-tri JtWJ | 6 rhs]; updates R,t in place.
// Unpivoted GE, fully unrolled (damped SPD -> stable).
__device__ __forceinline__ void solve_update(const float* sums, float R[9], float t[3]) {
    float M[6][7];
    {
        int idx = 0;
        #pragma unroll
        for (int k = 0; k < 6; k++)
            #pragma unroll
            for (int l = k; l < 6; l++) { M[k][l] = sums[idx]; M[l][k] = sums[idx]; idx++; }
    }
    const float trace = M[0][0]+M[1][1]+M[2][2]+M[3][3]+M[4][4]+M[5][5];
    const float lam = trace * 1e-6f;
    #pragma unroll
    for (int i = 0; i < 6; i++) { M[i][i] += lam; M[i][6] = sums[21+i]; }

    #pragma unroll
    for (int k = 0; k < 6; k++) {
        const float inv = 1.0f / M[k][k];
        #pragma unroll
        for (int i = k+1; i < 6; i++) {
            const float f = M[i][k] * inv;
            #pragma unroll
            for (int j = k; j < 7; j++) M[i][j] -= f * M[k][j];
        }
    }
    float xi[6];
    #pragma unroll
    for (int i = 5; i >= 0; i--) {
        float s = M[i][6];
        #pragma unroll
        for (int j = i+1; j < 6; j++) s -= M[i][j]*xi[j];
        xi[i] = s / M[i][i];
    }

    float dR[9];
    twist2mat_dev(-xi[0], -xi[1], -xi[2], dR);
    const float dt0 = -(dR[0]*xi[3] + dR[1]*xi[4] + dR[2]*xi[5]);
    const float dt1 = -(dR[3]*xi[3] + dR[4]*xi[4] + dR[5]*xi[5]);
    const float dt2 = -(dR[6]*xi[3] + dR[7]*xi[4] + dR[8]*xi[5]);

    const float nt0 = R[0]*dt0 + R[1]*dt1 + R[2]*dt2 + t[0];
    const float nt1 = R[3]*dt0 + R[4]*dt1 + R[5]*dt2 + t[1];
    const float nt2 = R[6]*dt0 + R[7]*dt1 + R[8]*dt2 + t[2];
    float nR[9];
    #pragma unroll
    for (int i = 0; i < 3; i++)
        #pragma unroll
        for (int j = 0; j < 3; j++)
            nR[i*3+j] = R[i*3+0]*dR[0*3+j] + R[i*3+1]*dR[1*3+j] + R[i*3+2]*dR[2*3+j];
    #pragma unroll
    for (int i = 0; i < 9; i++) R[i] = nR[i];
    t[0] = nt0; t[1] = nt1; t[2] = nt2;
}

// Precompute packed tensors; block (0,0,0) also zeroes accum/tickets and seeds RTbuf[0].
//  P0h  : [b][cp=0..7][pix] uint4 = {h2(gx,gy), h2(x0,s0^2)} x 2 channels
//  X1S1h: [b][cg=0..3][pix] uint4 = h2(x1,s1) x 4 channels (gather target)
__launch_bounds__(256)
__global__ void precompute_kernel(const float* __restrict__ x0, const float* __restrict__ x1,
                                  const float* __restrict__ sigma0, const float* __restrict__ sigma1,
                                  const float* __restrict__ twist0,
                                  uint4* __restrict__ P0h, uint4* __restrict__ X1S1h,
                                  float* __restrict__ accum, float* __restrict__ RTbuf,
                                  unsigned* __restrict__ tickets)
{
    if (blockIdx.x == 0 && blockIdx.y == 0 && blockIdx.z == 0) {
        for (int k = threadIdx.x; k < 3*B_*27; k += 256) accum[k] = 0.0f;
        if (threadIdx.x >= 64 && threadIdx.x < 64 + 3*B_) tickets[threadIdx.x - 64] = 0u;
        if (threadIdx.x < B_) {
            const float* w = twist0 + threadIdx.x*6;
            float R[9];
            twist2mat_dev(w[0], w[1], w[2], R);
            float* rt = RTbuf + (size_t)threadIdx.x*12;
            #pragma unroll
            for (int i = 0; i < 9; i++) rt[i] = R[i];
            rt[9] = w[3]; rt[10] = w[4]; rt[11] = w[5];
        }
    }
    const int pix = blockIdx.x*256 + threadIdx.x;
    const int cg = blockIdx.y;
    const int b = blockIdx.z;
    const int h = pix / W_, w = pix - h*W_;
    const int hm = max(h-1,0), hp = min(h+1,H_-1);
    const int wm = max(w-1,0), wp = min(w+1,W_-1);

    unsigned p0[8], xsp[4];
    #pragma unroll
    for (int i = 0; i < 4; i++) {
        const int c = cg*4 + i;
        const size_t base = ((size_t)(b*C_+c))*N_;
        const float* xc = x0 + base;
        const float tl = xc[hm*W_+wm], tc_ = xc[hm*W_+w], tr = xc[hm*W_+wp];
        const float ml = xc[h*W_+wm],                     mr = xc[h*W_+wp];
        const float bl = xc[hp*W_+wm], bc_ = xc[hp*W_+w], br = xc[hp*W_+wp];
        const float dx = tr - tl + 2.0f*(mr - ml) + (br - bl);
        const float dy = bl - tl + 2.0f*(bc_ - tc_) + (br - tr);
        const float mag = sqrtf(dx*dx + dy*dy + 1e-8f);
        const float s0v = sigma0[base + pix];
        p0[i*2+0] = pack_h2(dx/mag, dy/mag);
        p0[i*2+1] = pack_h2(xc[pix], s0v*s0v);
        xsp[i] = pack_h2(x1[base + pix], sigma1[base + pix]);
    }
    uint4 a; a.x = p0[0]; a.y = p0[1]; a.z = p0[2]; a.w = p0[3];
    uint4 bb; bb.x = p0[4]; bb.y = p0[5]; bb.z = p0[6]; bb.w = p0[7];
    P0h[((size_t)(b*8 + cg*2  ))*N_ + pix] = a;
    P0h[((size_t)(b*8 + cg*2+1))*N_ + pix] = bb;
    uint4 q; q.x = xsp[0]; q.y = xsp[1]; q.z = xsp[2]; q.w = xsp[3];
    X1S1h[((size_t)(b*4 + cg))*N_ + pix] = q;
}

// Lean iteration kernel: RT read as 12 uniform floats; packed fp16 gathers;
// block reduce -> atomics -> ticket -> last block solves and writes RT_{it+1}/out.
__launch_bounds__(256)
__global__ void iter_kernel(const uint4* __restrict__ P0h, const uint4* __restrict__ X1S1h,
                            const float* __restrict__ invD0, const float* __restrict__ invD1,
                            const float* __restrict__ Kmat,
                            float* __restrict__ accum, float* __restrict__ RTbuf,
                            unsigned* __restrict__ tickets, float* __restrict__ out, int it)
{
    const int b = blockIdx.y;
    const int pix = blockIdx.x*256 + threadIdx.x;
    const int tid = threadIdx.x;
    const int h = pix / W_;
    const int w = pix - h*W_;

    const float* rt = RTbuf + (size_t)(it*B_ + b)*12;
    const float R00=rt[0],R01=rt[1],R02=rt[2],R10=rt[3],R11=rt[4],R12=rt[5],
                R20=rt[6],R21=rt[7],R22=rt[8];
    const float t0=rt[9], t1=rt[10], t2=rt[11];
    const float fx = Kmat[b*4+0], fy = Kmat[b*4+1], cx = Kmat[b*4+2], cy = Kmat[b*4+3];

    const float px = ((float)w - cx) / fx;
    const float py = ((float)h - cy) / fy;
    const float d  = invD0[(size_t)b*N_ + pix];

    const float x_ = R00*px + R01*py + R02 + t0*d;
    const float y_ = R10*px + R11*py + R12 + t1*d;
    const float s_ = R20*px + R21*py + R22 + t2*d;
    const float u = x_/s_*fx + cx;
    const float v = y_/s_*fy + cy;
    const float inv_z = d / s_;

    const float uc = fminf(fmaxf(u, 0.0f), (float)(W_-1));
    const float vc = fminf(fmaxf(v, 0.0f), (float)(H_-1));
    const float x0f = floorf(uc), y0f = floorf(vc);
    const float wx = uc - x0f, wy = vc - y0f;
    const int x0i = (int)x0f, y0i = (int)y0f;
    const int x1i = min(x0i+1, W_-1), y1i = min(y0i+1, H_-1);
    const float w00 = (1.0f-wx)*(1.0f-wy), w01 = wx*(1.0f-wy);
    const float w10 = (1.0f-wx)*wy,        w11 = wx*wy;
    const int i00 = y0i*W_+x0i, i01 = y0i*W_+x1i, i10 = y1i*W_+x0i, i11 = y1i*W_+x1i;

    const float* dz = invD1 + (size_t)b*N_;
    const float zw = dz[i00]*w00 + dz[i01]*w01 + dz[i10]*w10 + dz[i11]*w11;
    const bool inlier = inv_z > zw - 0.1f;
    const bool inview = (u > 0.0f) && (u < (float)W_) && (v > 0.0f) && (v < (float)H_);

    float acc[27];
    #pragma unroll
    for (int j = 0; j < 27; j++) acc[j] = 0.0f;

    if (inlier && inview) {
        const float xy = px*py;
        const float Av[6] = { -xy*fx, (1.0f+px*px)*fx, -py*fx, d*fx, 0.0f, -d*px*fx };
        const float Bv[6] = { -(1.0f+py*py)*fy, xy*fy, px*fy, 0.0f, d*fy, -d*py*fy };

        float Swxx=0.f, Swxy=0.f, Swyy=0.f, Srx=0.f, Sry=0.f;
        const uint4* P0b   = P0h   + (size_t)b*8*N_;
        const uint4* X1S1b = X1S1h + (size_t)b*4*N_;

#define CH(gword, xword, t00, t01, t10, t11) { \
        const float2 g  = unpack_h2(gword); \
        const float2 xs = unpack_h2(xword); \
        const float2 a00 = unpack_h2(t00), a01 = unpack_h2(t01), \
                     a10 = unpack_h2(t10), a11 = unpack_h2(t11); \
        const float fr = a00.x*w00 + a01.x*w01 + a10.x*w10 + a11.x*w11; \
        const float sr = a00.y*w00 + a01.y*w01 + a10.y*w10 + a11.y*w11; \
        const float inv_s2 = 1.0f/(sr*sr + xs.y); \
        const float res = fr - xs.x; \
        const float gxw = g.x*inv_s2, gyw = g.y*inv_s2; \
        Swxx += g.x*gxw; Swxy += g.x*gyw; Swyy += g.y*gyw; \
        Srx  += res*gxw; Sry  += res*gyw; }

        #pragma unroll 2
        for (int cgi = 0; cgi < 4; cgi++) {
            const uint4 pA = P0b[(size_t)(cgi*2  )*N_ + pix];
            const uint4 pB = P0b[(size_t)(cgi*2+1)*N_ + pix];
            const uint4* xsb = X1S1b + (size_t)cgi*N_;
            const uint4 q00 = xsb[i00], q01 = xsb[i01], q10 = xsb[i10], q11 = xsb[i11];
            CH(pA.x, pA.y, q00.x, q01.x, q10.x, q11.x)
            CH(pA.z, pA.w, q00.y, q01.y, q10.y, q11.y)
            CH(pB.x, pB.y, q00.z, q01.z, q10.z, q11.z)
            CH(pB.z, pB.w, q00.w, q01.w, q10.w, q11.w)
        }
#undef CH

        int idx = 0;
        #pragma unroll
        for (int k = 0; k < 6; k++) {
            #pragma unroll
            for (int l = k; l < 6; l++) {
                acc[idx++] = Swxx*Av[k]*Av[l] + Swxy*(Av[k]*Bv[l] + Bv[k]*Av[l]) + Swyy*Bv[k]*Bv[l];
            }
        }
        #pragma unroll
        for (int k = 0; k < 6; k++) acc[21+k] = Srx*Av[k] + Sry*Bv[k];
    }

    // block reduction -> 27 atomics
    __shared__ float red[4][27];
    const int lane = tid & 63;
    const int wave = tid >> 6;
    #pragma unroll
    for (int j = 0; j < 27; j++) {
        float vv = acc[j];
        vv += __shfl_down(vv, 32);
        vv += __shfl_down(vv, 16);
        vv += __shfl_down(vv, 8);
        vv += __shfl_down(vv, 4);
        vv += __shfl_down(vv, 2);
        vv += __shfl_down(vv, 1);
        if (lane == 0) red[wave][j] = vv;
    }
    __syncthreads();
    float* ac = accum + (size_t)(it*B_ + b)*27;
    if (tid < 27) {
        float s = red[0][tid] + red[1][tid] + red[2][tid] + red[3][tid];
        atomicAdd(&ac[tid], s);
    }
    __syncthreads();   // drain all threads' accum atomics before ticketing

    __shared__ unsigned lastFlag;
    if (tid == 0) {
        __threadfence();
        unsigned prev = atomicAdd(&tickets[it*B_ + b], 1u);
        lastFlag = (prev == ITER_BLOCKS_PER_B - 1) ? 1u : 0u;
    }
    __syncthreads();

    if (lastFlag && tid < 64) {
        __threadfence();
        float sv = 0.0f;
        if (tid < 27) sv = atomicAdd(&ac[tid], 0.0f);   // device-coherent read
        float sums[27];
        #pragma unroll
        for (int j = 0; j < 27; j++) sums[j] = __shfl(sv, j);

        float R[9], t[3];
        #pragma unroll
        for (int i = 0; i < 9; i++) R[i] = rt[i];
        t[0] = rt[9]; t[1] = rt[10]; t[2] = rt[11];
        solve_update(sums, R, t);

        if (tid == 0) {
            float* dst = (it == 2) ? (out + b*12) : (RTbuf + (size_t)((it+1)*B_ + b)*12);
            #pragma unroll
            for (int i = 0; i < 9; i++) dst[i] = R[i];
            dst[9] = t[0]; dst[10] = t[1]; dst[11] = t[2];
        }
    }
}

extern "C" void kernel_launch(void* const* d_in, const int* in_sizes, int n_in,
                              void* d_out, int out_size, void* d_ws, size_t ws_size,
                              hipStream_t stream) {
    const float* twist0 = (const float*)d_in[0];
    const float* x0     = (const float*)d_in[1];
    const float* x1     = (const float*)d_in[2];
    const float* invD0  = (const float*)d_in[3];
    const float* invD1  = (const float*)d_in[4];
    const float* sigma0 = (const float*)d_in[5];
    const float* sigma1 = (const float*)d_in[6];
    const float* Kmat   = (const float*)d_in[7];
    float* out = (float*)d_out;

    const size_t p0_bytes = (size_t)B_*8*N_*sizeof(uint4);
    const size_t xs_bytes = (size_t)B_*4*N_*sizeof(uint4);

    uint4* P0h   = (uint4*)d_ws;
    uint4* X1S1h = (uint4*)((char*)d_ws + p0_bytes);
    float*    accum   = (float*)((char*)d_ws + p0_bytes + xs_bytes);  // 3*B*27
    float*    RTbuf   = accum + 3*B_*27;                              // 3*B*12
    unsigned* tickets = (unsigned*)(RTbuf + 3*B_*12);                 // 3*B

    hipLaunchKernelGGL(precompute_kernel, dim3(N_/256, 4, B_), dim3(256), 0, stream,
                       x0, x1, sigma0, sigma1, twist0, P0h, X1S1h, accum, RTbuf, tickets);

    dim3 grid(ITER_BLOCKS_PER_B, B_);
    for (int it = 0; it < 3; ++it) {
        hipLaunchKernelGGL(iter_kernel, grid, dim3(256), 0, stream,
                           P0h, X1S1h, invD0, invD1, Kmat,
                           accum, RTbuf, tickets, out, it);
    }
}